// Round 1
// baseline (459.178 us; speedup 1.0000x reference)
//
#include <hip/hip_runtime.h>
#include <math.h>

#define N_SLOTS 524288
#define DIM_MEM 128
#define DIM_IN 1024
#define NFACT 138
#define EPSF 1e-8f

// ws layout (bytes):
//   0    : float factors[138]        (atomically accumulated; zeroed each call)
//   1024 : float derived[16]         d0=key_s/max(key_norm,eps), d1..d7=shift_w, d8=sharpening
//   2048 : double S_acc; double P_acc
//   4096 : float e[N_SLOTS]
//   4096+4*N_SLOTS : float p[N_SLOTS]
// total ~4.2 MB

// ---- Stage 1: factors = x @ W + b  (1024 x 138) ----
__global__ __launch_bounds__(256) void k_factors(const float* __restrict__ x,
                                                 const float* __restrict__ W,
                                                 const float* __restrict__ b,
                                                 float* __restrict__ factors) {
    int j = threadIdx.x;            // factor column
    int i0 = blockIdx.x * 32;       // 32 input rows per block, 32 blocks
    if (j < NFACT) {
        float acc = 0.f;
        #pragma unroll 8
        for (int i = i0; i < i0 + 32; ++i)
            acc = fmaf(x[i], W[(size_t)i * NFACT + j], acc);   // consecutive j -> coalesced
        if (blockIdx.x == 0) acc += b[j];
        atomicAdd(&factors[j], acc);
    }
}

// ---- Stage 2: derived scalars ----
__global__ void k_derived(const float* __restrict__ f, float* __restrict__ d) {
    int l = threadIdx.x;            // 64 threads
    float v = f[l] * f[l] + f[l + 64] * f[l + 64];
    for (int off = 32; off; off >>= 1) v += __shfl_xor(v, off, 64);
    if (l == 0) {
        float key_norm = fmaxf(sqrtf(v), EPSF);
        float key_s = f[128];
        // gate = softmax over a single element == 1.0 exactly -> previous_weighting is dead
        d[0] = key_s / key_norm;
        float m = f[130];
        for (int j = 1; j < 7; ++j) m = fmaxf(m, f[130 + j]);
        float e[7], s = 0.f;
        for (int j = 0; j < 7; ++j) { e[j] = expf(f[130 + j] - m); s += e[j]; }
        for (int j = 0; j < 7; ++j) d[1 + j] = e[j] / s;
        d[8] = fmaxf(f[137], 0.f) + 1.f;   // sharpening
    }
}

// ---- Stage 3: pass 1 over memory: e_i = exp(key_s * cos(mem_i, key)), S = sum e ----
__global__ __launch_bounds__(256) void k_content(const float* __restrict__ mem,
                                                 const float* __restrict__ keyv,
                                                 const float* __restrict__ der,
                                                 float* __restrict__ e_out,
                                                 double* __restrict__ S_acc) {
    __shared__ float s_sum;
    if (threadIdx.x == 0) s_sum = 0.f;
    __syncthreads();
    const int lane = threadIdx.x & 31;   // half-wave lane: covers 4 cols
    const int hw   = threadIdx.x >> 5;   // 8 half-waves per block
    const float4 k4 = ((const float4*)keyv)[lane];
    const float d0 = der[0];
    float local = 0.f;
    const int stride = gridDim.x * 8;
    for (int r = blockIdx.x * 8 + hw; r < N_SLOTS; r += stride) {
        float4 m4 = ((const float4*)(mem + (size_t)r * DIM_MEM))[lane];
        float dot = m4.x * k4.x + m4.y * k4.y + m4.z * k4.z + m4.w * k4.w;
        float n2  = m4.x * m4.x + m4.y * m4.y + m4.z * m4.z + m4.w * m4.w;
        for (int off = 16; off; off >>= 1) {
            dot += __shfl_xor(dot, off, 32);
            n2  += __shfl_xor(n2,  off, 32);
        }
        if (lane == 0) {
            float score = d0 * dot / fmaxf(sqrtf(n2), EPSF);
            float e = expf(score);       // max-shift cancels in final normalization
            e_out[r] = e;
            local += e;
        }
    }
    if (lane == 0) atomicAdd(&s_sum, local);
    __syncthreads();
    if (threadIdx.x == 0) atomicAdd(S_acc, (double)s_sum);
}

// ---- Stage 4: circular 7-tap shift + sharpening: p_i = ((sum_d sw[d]*e[i+d-3])/S)^sh ----
__global__ __launch_bounds__(256) void k_shift(const float* __restrict__ e,
                                               const float* __restrict__ der,
                                               const double* __restrict__ S_acc,
                                               float* __restrict__ p_out,
                                               double* __restrict__ P_acc) {
    __shared__ float s_sum;
    if (threadIdx.x == 0) s_sum = 0.f;
    __syncthreads();
    const int i = blockIdx.x * blockDim.x + threadIdx.x;
    const float invS = (float)(1.0 / *S_acc);
    const float sh = der[8];
    float t = 0.f;
    #pragma unroll
    for (int d = 0; d < 7; ++d) {
        int idx = i + d - 3;
        if (idx < 0) idx += N_SLOTS;
        if (idx >= N_SLOTS) idx -= N_SLOTS;
        t = fmaf(der[1 + d], e[idx], t);
    }
    float p = powf(t * invS, sh);
    p_out[i] = p;
    float w = p;
    for (int off = 32; off; off >>= 1) w += __shfl_xor(w, off, 64);
    if ((threadIdx.x & 63) == 0) atomicAdd(&s_sum, w);
    __syncthreads();
    if (threadIdx.x == 0) atomicAdd(P_acc, (double)s_sum);
}

// ---- Stage 5: pass 2 over memory: out = sum_i (p_i/P) * mem_i ----
__global__ __launch_bounds__(256) void k_read(const float* __restrict__ mem,
                                              const float* __restrict__ p,
                                              const double* __restrict__ P_acc,
                                              float* __restrict__ out) {
    __shared__ float partials[8][DIM_MEM];
    const int lane = threadIdx.x & 31;
    const int hw   = threadIdx.x >> 5;
    const float invP = (float)(1.0 / *P_acc);
    float4 acc = make_float4(0.f, 0.f, 0.f, 0.f);
    const int stride = gridDim.x * 8;
    for (int r = blockIdx.x * 8 + hw; r < N_SLOTS; r += stride) {
        float w = p[r] * invP;           // same addr across half-wave -> broadcast
        float4 m4 = ((const float4*)(mem + (size_t)r * DIM_MEM))[lane];
        acc.x = fmaf(w, m4.x, acc.x);
        acc.y = fmaf(w, m4.y, acc.y);
        acc.z = fmaf(w, m4.z, acc.z);
        acc.w = fmaf(w, m4.w, acc.w);
    }
    ((float4*)partials[hw])[lane] = acc;
    __syncthreads();
    if (threadIdx.x < DIM_MEM) {
        float s = 0.f;
        #pragma unroll
        for (int h = 0; h < 8; ++h) s += partials[h][threadIdx.x];
        atomicAdd(&out[threadIdx.x], s);
    }
}

extern "C" void kernel_launch(void* const* d_in, const int* in_sizes, int n_in,
                              void* d_out, int out_size, void* d_ws, size_t ws_size,
                              hipStream_t stream) {
    const float* x   = (const float*)d_in[0];   // input_from_controller (1024)
    // d_in[1] = previous_weighting: unused — gate = softmax(single elem) == 1.0 exactly
    const float* mem = (const float*)d_in[2];   // memory (N_SLOTS*128)
    const float* W   = (const float*)d_in[3];   // W_wf (1024*138)
    const float* b   = (const float*)d_in[4];   // b_wf (138)
    float* out = (float*)d_out;

    char* ws = (char*)d_ws;
    float*  factors = (float*)ws;
    float*  derived = (float*)(ws + 1024);
    double* S_acc   = (double*)(ws + 2048);
    double* P_acc   = (double*)(ws + 2056);
    float*  e_buf   = (float*)(ws + 4096);
    float*  p_buf   = (float*)(ws + 4096 + (size_t)N_SLOTS * 4);

    hipMemsetAsync(ws, 0, 4096, stream);                       // factors + scalars + accumulators
    hipMemsetAsync(d_out, 0, DIM_MEM * sizeof(float), stream); // harness poisons d_out

    k_factors<<<DIM_IN / 32, 256, 0, stream>>>(x, W, b, factors);
    k_derived<<<1, 64, 0, stream>>>(factors, derived);
    k_content<<<1024, 256, 0, stream>>>(mem, factors, derived, e_buf, S_acc);
    k_shift<<<N_SLOTS / 256, 256, 0, stream>>>(e_buf, derived, S_acc, p_buf, P_acc);
    k_read<<<1024, 256, 0, stream>>>(mem, p_buf, P_acc, out);
}